// Round 1
// baseline (2602.203 us; speedup 1.0000x reference)
//
#include <hip/hip_runtime.h>

typedef unsigned short u16;
typedef unsigned int   u32;
typedef __bf16 bf16x8 __attribute__((ext_vector_type(8)));
typedef float  f32x4  __attribute__((ext_vector_type(4)));

// problem dims
#define DIMD  256
#define DIMH  512
#define MTILE 64          // rows per workgroup
#define NTHREADS 512      // 8 waves

// LDS layout in ushort units. Row strides padded +16B: stride(dwords)%32==8
// -> A-frag ds_read_b128 is 2-way bank aliased (free, m136).
#define USTR 272                       // u / k-scratch / k1 rows (256+16)
#define HSTR 528                       // h rows (512+16)
#define U_BASE 0
#define H_BASE (MTILE*USTR)            // 17408
#define K_BASE (H_BASE + MTILE*HSTR)   // 51200
#define LDS_U16 (K_BASE + MTILE*USTR)  // 68608 ushorts = 137216 B

#define DT 0.0625f

__device__ __forceinline__ u16 f2bf(float f) {          // RTN fp32->bf16
  u32 u = __float_as_uint(f);
  u += 0x7FFFu + ((u >> 16) & 1u);
  return (u16)(u >> 16);
}
__device__ __forceinline__ float bflo(u32 p) { return __uint_as_float(p << 16); }
__device__ __forceinline__ float bfhi(u32 p) { return __uint_as_float(p & 0xFFFF0000u); }
__device__ __forceinline__ float tanh_fast(float x) {
  // tanh(x) = 1 - 2/(1+e^{2x}); v_exp_f32 + v_rcp_f32, |err| ~1e-6 abs
  float e = __builtin_amdgcn_exp2f(x * 2.8853900817779268f);  // 2*log2(e)
  return 1.0f - 2.0f * __builtin_amdgcn_rcpf(e + 1.0f);
}

// Prologue: W1[256][512] -> W1T bf16 [n=512][k=256]; W2[512][256] -> W2T bf16 [n=256][k=512]
__global__ void convert_w(const float* __restrict__ W1, const float* __restrict__ W2,
                          u16* __restrict__ w1t, u16* __restrict__ w2t) {
  int idx = blockIdx.x * 256 + threadIdx.x;        // 0..131071, covers both
  {
    int n = idx >> 8, k = idx & 255;               // W1T[n][k] = W1[k][n]
    w1t[idx] = f2bf(W1[k * DIMH + n]);
  }
  {
    int n = idx >> 9, k = idx & 511;               // W2T[n][k] = W2[k][n]
    w2t[idx] = f2bf(W2[k * DIMD + n]);
  }
}

__global__ __launch_bounds__(NTHREADS, 2) void ode_fused(
    const float* __restrict__ x,   const float* __restrict__ b1,
    const float* __restrict__ b2,  const float* __restrict__ wfc,
    const float* __restrict__ bfc, const u16* __restrict__ w1t,
    const u16* __restrict__ w2t,   float* __restrict__ out)
{
  __shared__ u16 lds[LDS_U16];

  const int tid   = threadIdx.x;
  const int wg    = blockIdx.x;
  const int wv    = tid >> 6;          // wave 0..7 (N-split owner)
  const int lane  = tid & 63;
  const int lanel = lane & 15;
  const int laneq = lane >> 4;
  const int row   = tid >> 3;          // owner row 0..63
  const int c0    = (tid & 7) * 32;    // owner col base (32 cols/thread)

  // biases (per-wave columns), loaded once
  float b1v[4], b2v[2];
#pragma unroll
  for (int nb = 0; nb < 4; ++nb) b1v[nb] = b1[wv * 64 + nb * 16 + lanel];
#pragma unroll
  for (int nb = 0; nb < 2; ++nb) b2v[nb] = b2[wv * 32 + nb * 16 + lanel];

  // y carried in fp32 registers across all steps (precision anchor)
  float yv[32];
  {
    const float* xr = x + (wg * MTILE + row) * DIMD + c0;
#pragma unroll
    for (int i = 0; i < 32; ++i) yv[i] = xr[i];
  }

  // k2..k5 as packed bf16 pairs in registers (owner layout)
  u32 k2r[16], k3r[16], k4r[16], k5r[16];

#pragma unroll 1
  for (int step = 0; step < 16; ++step) {
#pragma unroll 1
    for (int s = 1; s <= 6; ++s) {
      // ---- owners: u_s = y + dt * sum A_sj k_j  -> bf16 -> LDS U region ----
      {
        float c1 = 0.f, c2 = 0.f, c3 = 0.f, c4 = 0.f, c5 = 0.f;
        switch (s) {
          case 2: c1 = DT * 0.2f; break;
          case 3: c1 = DT * 0.075f; c2 = DT * 0.225f; break;
          case 4: c1 = DT * (float)(44.0/45.0); c2 = DT * (float)(-56.0/15.0);
                  c3 = DT * (float)(32.0/9.0); break;
          case 5: c1 = DT * (float)(19372.0/6561.0); c2 = DT * (float)(-25360.0/2187.0);
                  c3 = DT * (float)(64448.0/6561.0); c4 = DT * (float)(-212.0/729.0); break;
          case 6: c1 = DT * (float)(9017.0/3168.0);  c2 = DT * (float)(-355.0/33.0);
                  c3 = DT * (float)(46732.0/5247.0); c4 = DT * (float)(49.0/176.0);
                  c5 = DT * (float)(-5103.0/18656.0); break;
          default: break;
        }
        u32* up = (u32*)&lds[U_BASE + row * USTR] + (c0 >> 1);
        const u32* k1p = (const u32*)&lds[K_BASE + row * USTR] + (c0 >> 1);
#pragma unroll
        for (int i = 0; i < 16; ++i) {
          float a0 = yv[2*i], a1 = yv[2*i+1];
          if (s >= 2) { u32 p = k1p[i];  a0 += c1 * bflo(p); a1 += c1 * bfhi(p); }
          if (s >= 3) { u32 p = k2r[i];  a0 += c2 * bflo(p); a1 += c2 * bfhi(p); }
          if (s >= 4) { u32 p = k3r[i];  a0 += c3 * bflo(p); a1 += c3 * bfhi(p); }
          if (s >= 5) { u32 p = k4r[i];  a0 += c4 * bflo(p); a1 += c4 * bfhi(p); }
          if (s >= 6) { u32 p = k5r[i];  a0 += c5 * bflo(p); a1 += c5 * bfhi(p); }
          up[i] = (u32)f2bf(a0) | ((u32)f2bf(a1) << 16);
        }
      }
      __syncthreads();   // u visible

      // ---- GEMM1: h_acc[64x512] = u @ W1 ; wave wv owns cols [wv*64, wv*64+64) ----
      f32x4 acc[4][4];
#pragma unroll
      for (int mb = 0; mb < 4; ++mb)
#pragma unroll
        for (int nb = 0; nb < 4; ++nb) acc[mb][nb] = (f32x4){0.f, 0.f, 0.f, 0.f};
#pragma unroll
      for (int kk = 0; kk < 8; ++kk) {
        bf16x8 a[4], b[4];
#pragma unroll
        for (int mb = 0; mb < 4; ++mb)
          a[mb] = *(const bf16x8*)&lds[U_BASE + (mb*16 + lanel) * USTR + kk*32 + laneq*8];
#pragma unroll
        for (int nb = 0; nb < 4; ++nb)
          b[nb] = *(const bf16x8*)&w1t[(wv*64 + nb*16 + lanel) * DIMD + kk*32 + laneq*8];
#pragma unroll
        for (int mb = 0; mb < 4; ++mb)
#pragma unroll
          for (int nb = 0; nb < 4; ++nb)
            acc[mb][nb] = __builtin_amdgcn_mfma_f32_16x16x32_bf16(a[mb], b[nb], acc[mb][nb], 0, 0, 0);
      }
      // epilogue1: +b1, tanh, bf16 -> h (separate LDS region; u may still be read by others)
#pragma unroll
      for (int nb = 0; nb < 4; ++nb) {
        int col = wv*64 + nb*16 + lanel;
#pragma unroll
        for (int mb = 0; mb < 4; ++mb)
#pragma unroll
          for (int r = 0; r < 4; ++r) {
            float v = tanh_fast(acc[mb][nb][r] + b1v[nb]);
            lds[H_BASE + (mb*16 + laneq*4 + r) * HSTR + col] = f2bf(v);
          }
      }
      __syncthreads();   // h visible; all GEMM1 u-reads done

      // ---- GEMM2: k_acc[64x256] = h @ W2 ; wave wv owns cols [wv*32, wv*32+32) ----
      f32x4 acc2[4][2];
#pragma unroll
      for (int mb = 0; mb < 4; ++mb)
#pragma unroll
        for (int nb = 0; nb < 2; ++nb) acc2[mb][nb] = (f32x4){0.f, 0.f, 0.f, 0.f};
#pragma unroll
      for (int kk = 0; kk < 16; ++kk) {
        bf16x8 a[4], b[2];
#pragma unroll
        for (int mb = 0; mb < 4; ++mb)
          a[mb] = *(const bf16x8*)&lds[H_BASE + (mb*16 + lanel) * HSTR + kk*32 + laneq*8];
#pragma unroll
        for (int nb = 0; nb < 2; ++nb)
          b[nb] = *(const bf16x8*)&w2t[(wv*32 + nb*16 + lanel) * DIMH + kk*32 + laneq*8];
#pragma unroll
        for (int mb = 0; mb < 4; ++mb)
#pragma unroll
          for (int nb = 0; nb < 2; ++nb)
            acc2[mb][nb] = __builtin_amdgcn_mfma_f32_16x16x32_bf16(a[mb], b[nb], acc2[mb][nb], 0, 0, 0);
      }
      // epilogue2: k_s = acc2 + b2 -> bf16. s==1 -> K region (k1 home); s>=2 -> U region (scratch; u dead)
      {
        int kb = (s == 1) ? K_BASE : U_BASE;
#pragma unroll
        for (int nb = 0; nb < 2; ++nb) {
          int col = wv*32 + nb*16 + lanel;
#pragma unroll
          for (int mb = 0; mb < 4; ++mb)
#pragma unroll
            for (int r = 0; r < 4; ++r)
              lds[kb + (mb*16 + laneq*4 + r) * USTR + col] = f2bf(acc2[mb][nb][r] + b2v[nb]);
        }
      }
      __syncthreads();   // k_s visible; all GEMM2 h-reads done

      // ---- owners: copy k_s (s=2..5) from scratch into registers ----
      {
        const u32* sp = (const u32*)&lds[U_BASE + row * USTR] + (c0 >> 1);
        if (s == 2) {
#pragma unroll
          for (int i = 0; i < 16; ++i) k2r[i] = sp[i];
        } else if (s == 3) {
#pragma unroll
          for (int i = 0; i < 16; ++i) k3r[i] = sp[i];
        } else if (s == 4) {
#pragma unroll
          for (int i = 0; i < 16; ++i) k4r[i] = sp[i];
        } else if (s == 5) {
#pragma unroll
          for (int i = 0; i < 16; ++i) k5r[i] = sp[i];
        }
      }
    } // stages

    // ---- y += dt*(B1 k1 + B3 k3 + B4 k4 + B5 k5 + B6 k6) ; k6 in U scratch, k1 in K ----
    {
      const u32* k1p = (const u32*)&lds[K_BASE + row * USTR] + (c0 >> 1);
      const u32* k6p = (const u32*)&lds[U_BASE + row * USTR] + (c0 >> 1);
      const float B1 = DT * (float)(35.0/384.0);
      const float B3 = DT * (float)(500.0/1113.0);
      const float B4 = DT * (float)(125.0/192.0);
      const float B5 = DT * (float)(-2187.0/6784.0);
      const float B6 = DT * (float)(11.0/84.0);
#pragma unroll
      for (int i = 0; i < 16; ++i) {
        u32 p1 = k1p[i], p3 = k3r[i], p4 = k4r[i], p5 = k5r[i], p6 = k6p[i];
        yv[2*i]   += B1*bflo(p1) + B3*bflo(p3) + B4*bflo(p4) + B5*bflo(p5) + B6*bflo(p6);
        yv[2*i+1] += B1*bfhi(p1) + B3*bfhi(p3) + B4*bfhi(p4) + B5*bfhi(p5) + B6*bfhi(p6);
      }
    }
  } // steps

  // ---- out[row] = y . Wfc + bfc, fp32; reduce 8 owner threads per row ----
  {
    float p = 0.f;
#pragma unroll
    for (int i = 0; i < 32; ++i) p += yv[i] * wfc[c0 + i];
    p += __shfl_xor(p, 1);
    p += __shfl_xor(p, 2);
    p += __shfl_xor(p, 4);
    if ((tid & 7) == 0) out[wg * MTILE + row] = p + bfc[0];
  }
}

extern "C" void kernel_launch(void* const* d_in, const int* in_sizes, int n_in,
                              void* d_out, int out_size, void* d_ws, size_t ws_size,
                              hipStream_t stream) {
  const float* x   = (const float*)d_in[0];
  const float* W1  = (const float*)d_in[1];
  const float* b1  = (const float*)d_in[2];
  const float* W2  = (const float*)d_in[3];
  const float* b2  = (const float*)d_in[4];
  const float* wfc = (const float*)d_in[5];
  const float* bfc = (const float*)d_in[6];
  float* out = (float*)d_out;

  u16* w1t = (u16*)d_ws;                 // [512][256] bf16
  u16* w2t = w1t + DIMH * DIMD;          // [256][512] bf16

  hipLaunchKernelGGL(convert_w, dim3(512), dim3(256), 0, stream, W1, W2, w1t, w2t);
  hipLaunchKernelGGL(ode_fused, dim3(16384 / MTILE), dim3(NTHREADS), 0, stream,
                     x, b1, b2, wfc, bfc, w1t, w2t, out);
}